// Round 10
// baseline (461.834 us; speedup 1.0000x reference)
//
#include <hip/hip_runtime.h>
#include <hip/hip_bf16.h>
#include <cmath>

// Problem constants
#define BSZ      256
#define D_IN     2048
#define D_OUT    2048
#define MG       1024      // M_GROUPS
#define NC       8         // N_CELLS
#define TOTAL    8192      // MG*NC
#define KGRP     128       // K_GROUPS (top-k groups)

typedef short bf16x8 __attribute__((ext_vector_type(8)));
typedef short s16x4  __attribute__((ext_vector_type(4)));
typedef float f32x4  __attribute__((ext_vector_type(4)));

// fp32 <-> bf16 helpers (round-to-nearest-even, bit ops, deterministic)
__device__ inline short f2bf(float f) {
    unsigned u = __float_as_uint(f);
    unsigned r = (u + 0x7fffu + ((u >> 16) & 1u)) >> 16;
    return (short)r;
}
__device__ inline float bf2f(short s) {
    return __uint_as_float(((unsigned)(unsigned short)s) << 16);
}

// ===========================================================================
// fp32 tiled GEMM (z_a producer — decision-grade accuracy — and fallback)
// ===========================================================================
#define TILE 64
#define BK   32

template <int MODE>
__global__ __launch_bounds__(256) void gemm_f32(
    const float* __restrict__ A, const float* __restrict__ B,
    const float* __restrict__ bias, const float* __restrict__ aux,
    float* __restrict__ C, int M, int N, int K)
{
    __shared__ float As[BK][TILE + 4];
    __shared__ float Bs[BK][TILE];

    const int tid = threadIdx.x;
    const int tx = tid & 15;
    const int ty = tid >> 4;
    const int n0 = blockIdx.x * TILE;
    const int m0 = blockIdx.y * TILE;

    float acc[4][4] = {};

    for (int k0 = 0; k0 < K; k0 += BK) {
        #pragma unroll
        for (int it = 0; it < 2; ++it) {
            int lin = tid + it * 256;
            int row = lin >> 3;
            int c4  = lin & 7;
            float4 a = *(const float4*)&A[(size_t)(m0 + row) * K + k0 + c4 * 4];
            As[c4 * 4 + 0][row] = a.x;
            As[c4 * 4 + 1][row] = a.y;
            As[c4 * 4 + 2][row] = a.z;
            As[c4 * 4 + 3][row] = a.w;
        }
        #pragma unroll
        for (int it = 0; it < 2; ++it) {
            int lin = tid + it * 256;
            int row = lin >> 4;
            int c4  = lin & 15;
            *(float4*)&Bs[row][c4 * 4] =
                *(const float4*)&B[(size_t)(k0 + row) * N + n0 + c4 * 4];
        }
        __syncthreads();

        #pragma unroll
        for (int k = 0; k < BK; ++k) {
            float4 av = *(const float4*)&As[k][ty * 4];
            float4 bv = *(const float4*)&Bs[k][tx * 4];
            float a_[4] = {av.x, av.y, av.z, av.w};
            float b_[4] = {bv.x, bv.y, bv.z, bv.w};
            #pragma unroll
            for (int i = 0; i < 4; ++i)
                #pragma unroll
                for (int j = 0; j < 4; ++j)
                    acc[i][j] = fmaf(a_[i], b_[j], acc[i][j]);
        }
        __syncthreads();
    }

    #pragma unroll
    for (int i = 0; i < 4; ++i) {
        int m = m0 + ty * 4 + i;
        int n = n0 + tx * 4;
        float4 out;
        float* o = (float*)&out;
        #pragma unroll
        for (int j = 0; j < 4; ++j) {
            float v = acc[i][j] + bias[n + j];
            if (MODE == 1) v = aux[(size_t)m * MG + ((n + j) >> 3)] + v;
            o[j] = v;
        }
        *(float4*)&C[(size_t)m * N + n] = out;
    }
}

__global__ __launch_bounds__(256) void block_min(
    const float* __restrict__ x, int n, float* __restrict__ out)
{
    __shared__ float red[256];
    float v = 3.402823466e+38f;
    for (int i = blockIdx.x * 256 + threadIdx.x; i < n; i += gridDim.x * 256)
        v = fminf(v, x[i]);
    red[threadIdx.x] = v;
    __syncthreads();
    for (int s = 128; s > 0; s >>= 1) {
        if (threadIdx.x < s)
            red[threadIdx.x] = fminf(red[threadIdx.x], red[threadIdx.x + s]);
        __syncthreads();
    }
    if (threadIdx.x == 0) out[blockIdx.x] = red[0];
}

__global__ __launch_bounds__(512) void row_kernel(
    const float* __restrict__ sigma, const float* __restrict__ phi,
    const float* __restrict__ psi, const float* __restrict__ minval,
    float* __restrict__ decode, float* __restrict__ xb_new,
    float* __restrict__ phi_new, float* __restrict__ psi_new)
{
    __shared__ unsigned long long keys[MG];
    __shared__ int acell[MG];
    __shared__ int win[MG];

    const int b = blockIdx.x;
    const int tid = threadIdx.x;
    const float smin = minval[0];
    const float* srow = sigma + (size_t)b * TOTAL;
    const float* prow = phi + (size_t)b * TOTAL;
    const float* qrow = psi + (size_t)b * TOTAL;

    for (int g = tid; g < MG; g += 512) {
        float best = -3.402823466e+38f;
        int bc = 0;
        #pragma unroll
        for (int c = 0; c < NC; ++c) {
            float s = srow[g * NC + c];
            float p = prow[g * NC + c];
            float pi = (1.0f - p) * ((s - smin) + 1.0f);
            if (pi > best) { best = pi; bc = c; }
        }
        unsigned int bits = __float_as_uint(best);
        unsigned int u = (bits & 0x80000000u) ? ~bits : (bits | 0x80000000u);
        keys[g] = ((unsigned long long)(~u) << 32) | (unsigned int)g;
        acell[g] = bc;
        win[g] = 0;
    }
    __syncthreads();

    for (int k = 2; k <= MG; k <<= 1) {
        for (int j = k >> 1; j > 0; j >>= 1) {
            for (int t = tid; t < MG; t += 512) {
                int ixj = t ^ j;
                if (ixj > t) {
                    unsigned long long a = keys[t], bb_ = keys[ixj];
                    bool asc = ((t & k) == 0);
                    if ((a > bb_) == asc) { keys[t] = bb_; keys[ixj] = a; }
                }
            }
            __syncthreads();
        }
    }
    if (tid < KGRP) {
        int g = (int)(keys[tid] & 0xFFFFFFFFu);
        win[g] = 1;
    }
    __syncthreads();

    for (int j = tid; j < TOTAL; j += 512) {
        int g = j >> 3, c = j & 7;
        float s = srow[j];
        float y = 0.0f;
        if (win[g] && acell[g] == c) y = tanhf(s);
        float pn = fmaxf(prow[j] * 0.5f, y);
        float qn = fmaxf(qrow[j] * 0.5f, y);
        phi_new[(size_t)b * TOTAL + j] = pn;
        psi_new[(size_t)b * TOTAL + j] = qn;
        xb_new[(size_t)b * TOTAL + j] = qn;
    }

    for (int g = tid; g < MG; g += 512) {
        float d = 0.0f;
        if (win[g]) d = fmaxf(0.0f, tanhf(srow[g * NC + acell[g]]));
        decode[(size_t)b * MG + g] = d;
    }
}

// ===========================================================================
// bf16x3 MFMA GEMM: part[kslice] = A[all 256 rows, kslice] @ B[kslice, ntile]
// BM=256 (FULL M — Wb streamed/converted exactly once), BN=256, BK=64.
// 1024 threads = 16 waves (4x4), wave tile 64x64, acc[4][4] (<=128 VGPR ->
// 4 waves/SIMD). B double-buffered in 128 KB LDS; convert happens AFTER the
// barrier (f regs don't overlap frag regs across compute). Raw s_barrier +
// lgkmcnt only (r8-proven): prefetch stays in flight across barriers.
// Total K-steps chip-wide halved vs r8 (4096): the quantity time tracked
// across r5-r9. Partials: slices [0,SPLITZ) at part_w, rest at part_d.
// ===========================================================================
__global__ __launch_bounds__(256) void convert_bf(
    const float* __restrict__ src, short* __restrict__ h, short* __restrict__ l,
    int nchunks)
{
    for (int t = blockIdx.x * 256 + threadIdx.x; t < nchunks; t += gridDim.x * 256) {
        size_t idx = (size_t)t * 8;
        float4 v0 = *(const float4*)&src[idx];
        float4 v1 = *(const float4*)&src[idx + 4];
        float vv[8] = {v0.x, v0.y, v0.z, v0.w, v1.x, v1.y, v1.z, v1.w};
        bf16x8 hv, lv;
        #pragma unroll
        for (int e = 0; e < 8; ++e) {
            short hh = f2bf(vv[e]);
            hv[e] = hh;
            lv[e] = f2bf(vv[e] - bf2f(hh));
        }
        *(bf16x8*)&h[idx] = hv;
        *(bf16x8*)&l[idx] = lv;
    }
}

template <int KD, int BSTRIDE, int KPER, int SPLITZ, int SLICE>
__global__ __launch_bounds__(1024, 1) void gemm_mfma(
    const short* __restrict__ Ah_g, const short* __restrict__ Al_g,
    const float* __restrict__ Bg, float* __restrict__ part_w,
    float* __restrict__ part_d)
{
    // [buf][n][8 chunks of 8k], chunk pos = kc ^ (n&7)  (proven r3 swizzle)
    __shared__ short Bh[2][256 * 64];   // 64 KB
    __shared__ short Bl[2][256 * 64];   // 64 KB

    const int tid = threadIdx.x;
    const int l = tid & 63;
    const int w = tid >> 6;             // 0..15
    const int wr = w >> 2;              // wave row band (0..3), 64 rows
    const int wc = w & 3;               // wave col band (0..3), 64 cols
    const int n0 = blockIdx.x * 256;
    const int k0 = blockIdx.z * KPER;
    constexpr int NSTEP = KPER / 64;

    // staging map: thread covers 4 k-rows x 4 n (16 elems), all 1024 stage
    const int khalf = tid & 1;          // half-chunk (4 k)
    const int kc    = (tid >> 1) & 7;   // 8-k chunk
    const int n4    = (tid >> 4) * 4;   // n quad (0..252)

    f32x4 acc[4][4] = {};
    float4 f[4];

    // prologue: load + convert step 0 into buf 0; issue step-1 loads
    #pragma unroll
    for (int it = 0; it < 4; ++it)
        f[it] = *(const float4*)&Bg[(size_t)(k0 + kc * 8 + khalf * 4 + it) * BSTRIDE + n0 + n4];
    #pragma unroll
    for (int j = 0; j < 4; ++j) {
        s16x4 hv, lv;
        #pragma unroll
        for (int it = 0; it < 4; ++it) {
            float v = ((const float*)&f[it])[j];
            short hh = f2bf(v);
            hv[it] = hh;
            lv[it] = f2bf(v - bf2f(hh));
        }
        int n = n4 + j;
        int off = n * 64 + ((kc ^ (n & 7)) * 8) + khalf * 4;
        *(s16x4*)&Bh[0][off] = hv;
        *(s16x4*)&Bl[0][off] = lv;
    }
    if (NSTEP > 1) {
        #pragma unroll
        for (int it = 0; it < 4; ++it)
            f[it] = *(const float4*)&Bg[(size_t)(k0 + 64 + kc * 8 + khalf * 4 + it) * BSTRIDE + n0 + n4];
    }

    for (int st = 0; st < NSTEP; ++st) {
        const int cur = st & 1;
        const int kw = k0 + st * 64;

        // own LDS writes (convert of buf[cur], done last iter / prologue)
        // must be drained; do NOT drain vmcnt (prefetch stays in flight).
        asm volatile("s_waitcnt lgkmcnt(0)" ::: "memory");
        __builtin_amdgcn_sched_barrier(0);
        __builtin_amdgcn_s_barrier();
        __builtin_amdgcn_sched_barrier(0);

        // convert step st+1 into buf[cur^1] (its last readers passed the
        // barrier above); f regs die here, before frag regs go live.
        if (st + 1 < NSTEP) {
            #pragma unroll
            for (int j = 0; j < 4; ++j) {
                s16x4 hv, lv;
                #pragma unroll
                for (int it = 0; it < 4; ++it) {
                    float v = ((const float*)&f[it])[j];
                    short hh = f2bf(v);
                    hv[it] = hh;
                    lv[it] = f2bf(v - bf2f(hh));
                }
                int n = n4 + j;
                int off = n * 64 + ((kc ^ (n & 7)) * 8) + khalf * 4;
                *(s16x4*)&Bh[cur ^ 1][off] = hv;
                *(s16x4*)&Bl[cur ^ 1][off] = lv;
            }
        }
        // issue loads for step st+2 (hide HBM under this step's compute)
        if (st + 2 < NSTEP) {
            const int kn = kw + 128;
            #pragma unroll
            for (int it = 0; it < 4; ++it)
                f[it] = *(const float4*)&Bg[(size_t)(kn + kc * 8 + khalf * 4 + it) * BSTRIDE + n0 + n4];
        }

        // compute step st: A-frags direct from global planes; B from LDS
        #pragma unroll
        for (int kk = 0; kk < 2; ++kk) {
            const int chunk = kk * 4 + (l >> 4);
            bf16x8 ah[4], al[4];
            #pragma unroll
            for (int mt = 0; mt < 4; ++mt) {
                int row = wr * 64 + mt * 16 + (l & 15);
                size_t g = (size_t)row * KD + kw + chunk * 8;
                ah[mt] = *(const bf16x8*)&Ah_g[g];
                al[mt] = *(const bf16x8*)&Al_g[g];
            }
            #pragma unroll
            for (int nt = 0; nt < 4; ++nt) {
                int n = wc * 64 + nt * 16 + (l & 15);
                int off = n * 64 + ((chunk ^ (n & 7)) * 8);
                bf16x8 bh = *(const bf16x8*)&Bh[cur][off];
                bf16x8 bl = *(const bf16x8*)&Bl[cur][off];
                #pragma unroll
                for (int mt = 0; mt < 4; ++mt) {
                    acc[mt][nt] = __builtin_amdgcn_mfma_f32_16x16x32_bf16(
                        ah[mt], bh, acc[mt][nt], 0, 0, 0);
                    acc[mt][nt] = __builtin_amdgcn_mfma_f32_16x16x32_bf16(
                        ah[mt], bl, acc[mt][nt], 0, 0, 0);
                    acc[mt][nt] = __builtin_amdgcn_mfma_f32_16x16x32_bf16(
                        al[mt], bh, acc[mt][nt], 0, 0, 0);
                }
            }
        }
        // no trailing barrier: next iteration's convert targets the OTHER
        // buffer, and a wave is at most one barrier ahead of its siblings.
    }

    // Epilogue: D layout col = lane&15, row = (lane>>4)*4 + reg
    const int z = blockIdx.z;
    float* P = (z < SPLITZ) ? (part_w + (size_t)z * SLICE)
                            : (part_d + (size_t)(z - SPLITZ) * SLICE);
    #pragma unroll
    for (int mt = 0; mt < 4; ++mt) {
        int m = wr * 64 + mt * 16 + (l >> 4) * 4;
        #pragma unroll
        for (int nt = 0; nt < 4; ++nt) {
            int n = n0 + wc * 64 + nt * 16 + (l & 15);
            #pragma unroll
            for (int r = 0; r < 4; ++r)
                P[(size_t)(m + r) * BSTRIDE + n] = acc[mt][nt][r];
        }
    }
}

// Partial reduce + bias (+ z_a repeat + global-min for MODE 1).
// Slices 0..NSLW-1 at pw, then NSLD more at pd (fixed order -> deterministic).
// `out` may alias pw slice 0 (element-wise read-then-write) -> no __restrict__.
template <int NSLW, int NSLD, int NDIM, int MODE, int STR4>
__global__ __launch_bounds__(256) void reduce_part(
    const float* pw, const float* pd, const float* __restrict__ aux,
    const float* __restrict__ bias, float* out,
    float* __restrict__ bmin)
{
    __shared__ float red[256];
    int i = blockIdx.x * 256 + threadIdx.x;
    size_t b4 = (size_t)i * 4;
    float4 s = {0.f, 0.f, 0.f, 0.f};
    #pragma unroll
    for (int sl = 0; sl < NSLW; ++sl) {
        float4 p = *(const float4*)&pw[(size_t)sl * STR4 * 4 + b4];
        s.x += p.x; s.y += p.y; s.z += p.z; s.w += p.w;
    }
    #pragma unroll
    for (int sl = 0; sl < NSLD; ++sl) {
        float4 p = *(const float4*)&pd[(size_t)sl * STR4 * 4 + b4];
        s.x += p.x; s.y += p.y; s.z += p.z; s.w += p.w;
    }
    int col = (int)(b4 & (NDIM - 1));
    float4 bv = *(const float4*)&bias[col];
    float az = 0.f;
    if (MODE == 1) {
        int m = (int)(b4 >> 13);
        az = aux[m * MG + (col >> 3)];
    }
    s.x += bv.x + az; s.y += bv.y + az; s.z += bv.z + az; s.w += bv.w + az;
    *(float4*)&out[b4] = s;

    if (MODE == 1) {
        float v = fminf(fminf(s.x, s.y), fminf(s.z, s.w));
        red[threadIdx.x] = v;
        __syncthreads();
        for (int st = 128; st > 0; st >>= 1) {
            if (threadIdx.x < st)
                red[threadIdx.x] = fminf(red[threadIdx.x], red[threadIdx.x + st]);
            __syncthreads();
        }
        if (threadIdx.x == 0) bmin[blockIdx.x] = red[0];
    }
}

// ---------------------------------------------------------------------------
extern "C" void kernel_launch(void* const* d_in, const int* in_sizes, int n_in,
                              void* d_out, int out_size, void* d_ws, size_t ws_size,
                              hipStream_t stream)
{
    const float* x_a = (const float*)d_in[0];
    const float* x_b = (const float*)d_in[1];
    const float* phi = (const float*)d_in[2];
    const float* psi = (const float*)d_in[3];
    const float* Wa  = (const float*)d_in[4];
    const float* ba  = (const float*)d_in[5];
    const float* Wb  = (const float*)d_in[6];
    const float* bb  = (const float*)d_in[7];
    const float* Wd  = (const float*)d_in[8];
    const float* bd  = (const float*)d_in[9];

    float* out = (float*)d_out;
    float* pred    = out;
    float* xb_new  = out + BSZ * D_OUT;
    float* phi_new = out + BSZ * D_OUT + BSZ * TOTAL;
    float* psi_new = out + BSZ * D_OUT + 2 * BSZ * TOTAL;

    float* ws = (float*)d_ws;
    dim3 blk(256);
    dim3 blk512(512);
    dim3 blk1024(1024);

    // Workspace layout (float offsets); all 16B-aligned.
    const size_t OFF_ZA     = 0;            // 262144
    const size_t OFF_DECODE = 262144;       // 262144
    const size_t OFF_BMIN   = 524288;       // 2048
    const size_t OFF_MINV   = 526336;       // 16
    const size_t OFF_XBH    = 526352;       // 1048576 (2M shorts)
    const size_t OFF_XBL    = 1574928;      // 1048576
    const size_t OFF_PART   = 2623504;      // 10485760 floats (5 sigma slices)
    const size_t NEED = (OFF_PART + 10485760) * 4;   // 52437056 B == r3-proven

    if (ws_size >= NEED) {
        float* z_a    = ws + OFF_ZA;
        float* decode = ws + OFF_DECODE;
        float* bmin   = ws + OFF_BMIN;
        float* minv   = ws + OFF_MINV;
        short* xbh    = (short*)(ws + OFF_XBH);
        short* xbl    = (short*)(ws + OFF_XBL);
        short* dech   = xbh;                  // reuse (sigma gemm done by then)
        short* decl   = xbl;
        float* part_w = ws + OFF_PART;        // 5 slices of 2097152 floats
        float* part_d = out + BSZ * D_OUT;    // 3 slices in d_out (dead until
                                              // row_kernel overwrites them)
        float* sigma  = part_w;               // alias, slice 0

        // z_a = x_a @ Wa + ba  -- fp32 (decision-grade accuracy; feeds top-k)
        gemm_f32<0><<<dim3(MG / TILE, BSZ / TILE), blk, 0, stream>>>(
            x_a, Wa, ba, nullptr, z_a, BSZ, MG, D_IN);

        // sigma = repeat(z_a,8) + x_b @ Wb + bb  -- bf16x3 MFMA, BM=256/BN=256
        convert_bf<<<1024, blk, 0, stream>>>(x_b, xbh, xbl, BSZ * TOTAL / 8);
        gemm_mfma<TOTAL, TOTAL, 1024, 5, BSZ * TOTAL>
            <<<dim3(TOTAL / 256, 1, 8), blk1024, 0, stream>>>(
                xbh, xbl, Wb, part_w, part_d);
        reduce_part<5, 3, TOTAL, 1, 524288><<<2048, blk, 0, stream>>>(
            part_w, part_d, z_a, bb, sigma, bmin);
        block_min<<<1, blk, 0, stream>>>(bmin, 2048, minv);

        // masks, y, elementwise outputs, decode_in (consumes sigma; overwrites
        // the d_out partial slices, which are dead now)
        row_kernel<<<BSZ, blk512, 0, stream>>>(
            sigma, phi, psi, minv, decode, xb_new, phi_new, psi_new);

        // pred = decode @ Wd + bd  -- bf16x3 MFMA (no decisions downstream)
        convert_bf<<<128, blk, 0, stream>>>(decode, dech, decl, BSZ * MG / 8);
        gemm_mfma<MG, D_OUT, 64, 16, BSZ * D_OUT>
            <<<dim3(D_OUT / 256, 1, 16), blk1024, 0, stream>>>(
                dech, decl, Wd, part_w, part_w);
        reduce_part<16, 0, D_OUT, 2, 131072><<<512, blk, 0, stream>>>(
            part_w, part_w, nullptr, bd, pred, nullptr);
    } else {
        // Fallback: proven fp32 path (needs ~10.5 MB ws)
        float* z_a    = ws;
        float* sigma  = ws + 262144;
        float* decode = ws + 262144 + 2097152;
        float* bmin   = ws + 2621440;
        float* minv   = ws + 2622464;

        gemm_f32<0><<<dim3(MG / TILE, BSZ / TILE), blk, 0, stream>>>(
            x_a, Wa, ba, nullptr, z_a, BSZ, MG, D_IN);
        gemm_f32<1><<<dim3(TOTAL / TILE, BSZ / TILE), blk, 0, stream>>>(
            x_b, Wb, bb, z_a, sigma, BSZ, TOTAL, TOTAL);
        block_min<<<1024, blk, 0, stream>>>(sigma, BSZ * TOTAL, bmin);
        block_min<<<1, blk, 0, stream>>>(bmin, 1024, minv);
        row_kernel<<<BSZ, blk512, 0, stream>>>(
            sigma, phi, psi, minv, decode, xb_new, phi_new, psi_new);
        gemm_f32<0><<<dim3(D_OUT / TILE, BSZ / TILE), blk, 0, stream>>>(
            decode, Wd, bd, nullptr, pred, BSZ, D_OUT, MG);
    }
}

// Round 11
// 336.372 us; speedup vs baseline: 1.3730x; 1.3730x over previous
//
#include <hip/hip_runtime.h>
#include <hip/hip_bf16.h>
#include <cmath>

// Problem constants
#define BSZ      256
#define D_IN     2048
#define D_OUT    2048
#define MG       1024      // M_GROUPS
#define NC       8         // N_CELLS
#define TOTAL    8192      // MG*NC
#define KGRP     128       // K_GROUPS (top-k groups)

typedef short bf16x8 __attribute__((ext_vector_type(8)));
typedef short s16x4  __attribute__((ext_vector_type(4)));
typedef float f32x4  __attribute__((ext_vector_type(4)));

// fp32 <-> bf16 helpers (round-to-nearest-even, bit ops, deterministic)
__device__ inline short f2bf(float f) {
    unsigned u = __float_as_uint(f);
    unsigned r = (u + 0x7fffu + ((u >> 16) & 1u)) >> 16;
    return (short)r;
}
__device__ inline float bf2f(short s) {
    return __uint_as_float(((unsigned)(unsigned short)s) << 16);
}

// ===========================================================================
// fp32 tiled GEMM (z_a producer — decision-grade accuracy — and fallback)
// ===========================================================================
#define TILE 64
#define BK   32

template <int MODE>
__global__ __launch_bounds__(256) void gemm_f32(
    const float* __restrict__ A, const float* __restrict__ B,
    const float* __restrict__ bias, const float* __restrict__ aux,
    float* __restrict__ C, int M, int N, int K)
{
    __shared__ float As[BK][TILE + 4];
    __shared__ float Bs[BK][TILE];

    const int tid = threadIdx.x;
    const int tx = tid & 15;
    const int ty = tid >> 4;
    const int n0 = blockIdx.x * TILE;
    const int m0 = blockIdx.y * TILE;

    float acc[4][4] = {};

    for (int k0 = 0; k0 < K; k0 += BK) {
        #pragma unroll
        for (int it = 0; it < 2; ++it) {
            int lin = tid + it * 256;
            int row = lin >> 3;
            int c4  = lin & 7;
            float4 a = *(const float4*)&A[(size_t)(m0 + row) * K + k0 + c4 * 4];
            As[c4 * 4 + 0][row] = a.x;
            As[c4 * 4 + 1][row] = a.y;
            As[c4 * 4 + 2][row] = a.z;
            As[c4 * 4 + 3][row] = a.w;
        }
        #pragma unroll
        for (int it = 0; it < 2; ++it) {
            int lin = tid + it * 256;
            int row = lin >> 4;
            int c4  = lin & 15;
            *(float4*)&Bs[row][c4 * 4] =
                *(const float4*)&B[(size_t)(k0 + row) * N + n0 + c4 * 4];
        }
        __syncthreads();

        #pragma unroll
        for (int k = 0; k < BK; ++k) {
            float4 av = *(const float4*)&As[k][ty * 4];
            float4 bv = *(const float4*)&Bs[k][tx * 4];
            float a_[4] = {av.x, av.y, av.z, av.w};
            float b_[4] = {bv.x, bv.y, bv.z, bv.w};
            #pragma unroll
            for (int i = 0; i < 4; ++i)
                #pragma unroll
                for (int j = 0; j < 4; ++j)
                    acc[i][j] = fmaf(a_[i], b_[j], acc[i][j]);
        }
        __syncthreads();
    }

    #pragma unroll
    for (int i = 0; i < 4; ++i) {
        int m = m0 + ty * 4 + i;
        int n = n0 + tx * 4;
        float4 out;
        float* o = (float*)&out;
        #pragma unroll
        for (int j = 0; j < 4; ++j) {
            float v = acc[i][j] + bias[n + j];
            if (MODE == 1) v = aux[(size_t)m * MG + ((n + j) >> 3)] + v;
            o[j] = v;
        }
        *(float4*)&C[(size_t)m * N + n] = out;
    }
}

__global__ __launch_bounds__(256) void block_min(
    const float* __restrict__ x, int n, float* __restrict__ out)
{
    __shared__ float red[256];
    float v = 3.402823466e+38f;
    for (int i = blockIdx.x * 256 + threadIdx.x; i < n; i += gridDim.x * 256)
        v = fminf(v, x[i]);
    red[threadIdx.x] = v;
    __syncthreads();
    for (int s = 128; s > 0; s >>= 1) {
        if (threadIdx.x < s)
            red[threadIdx.x] = fminf(red[threadIdx.x], red[threadIdx.x + s]);
        __syncthreads();
    }
    if (threadIdx.x == 0) out[blockIdx.x] = red[0];
}

__global__ __launch_bounds__(512) void row_kernel(
    const float* __restrict__ sigma, const float* __restrict__ phi,
    const float* __restrict__ psi, const float* __restrict__ minval,
    float* __restrict__ decode, float* __restrict__ xb_new,
    float* __restrict__ phi_new, float* __restrict__ psi_new)
{
    __shared__ unsigned long long keys[MG];
    __shared__ int acell[MG];
    __shared__ int win[MG];

    const int b = blockIdx.x;
    const int tid = threadIdx.x;
    const float smin = minval[0];
    const float* srow = sigma + (size_t)b * TOTAL;
    const float* prow = phi + (size_t)b * TOTAL;
    const float* qrow = psi + (size_t)b * TOTAL;

    for (int g = tid; g < MG; g += 512) {
        float best = -3.402823466e+38f;
        int bc = 0;
        #pragma unroll
        for (int c = 0; c < NC; ++c) {
            float s = srow[g * NC + c];
            float p = prow[g * NC + c];
            float pi = (1.0f - p) * ((s - smin) + 1.0f);
            if (pi > best) { best = pi; bc = c; }
        }
        unsigned int bits = __float_as_uint(best);
        unsigned int u = (bits & 0x80000000u) ? ~bits : (bits | 0x80000000u);
        keys[g] = ((unsigned long long)(~u) << 32) | (unsigned int)g;
        acell[g] = bc;
        win[g] = 0;
    }
    __syncthreads();

    for (int k = 2; k <= MG; k <<= 1) {
        for (int j = k >> 1; j > 0; j >>= 1) {
            for (int t = tid; t < MG; t += 512) {
                int ixj = t ^ j;
                if (ixj > t) {
                    unsigned long long a = keys[t], bb_ = keys[ixj];
                    bool asc = ((t & k) == 0);
                    if ((a > bb_) == asc) { keys[t] = bb_; keys[ixj] = a; }
                }
            }
            __syncthreads();
        }
    }
    if (tid < KGRP) {
        int g = (int)(keys[tid] & 0xFFFFFFFFu);
        win[g] = 1;
    }
    __syncthreads();

    for (int j = tid; j < TOTAL; j += 512) {
        int g = j >> 3, c = j & 7;
        float s = srow[j];
        float y = 0.0f;
        if (win[g] && acell[g] == c) y = tanhf(s);
        float pn = fmaxf(prow[j] * 0.5f, y);
        float qn = fmaxf(qrow[j] * 0.5f, y);
        phi_new[(size_t)b * TOTAL + j] = pn;
        psi_new[(size_t)b * TOTAL + j] = qn;
        xb_new[(size_t)b * TOTAL + j] = qn;
    }

    for (int g = tid; g < MG; g += 512) {
        float d = 0.0f;
        if (win[g]) d = fmaxf(0.0f, tanhf(srow[g * NC + acell[g]]));
        decode[(size_t)b * MG + g] = d;
    }
}

// ===========================================================================
// A-plane conversion, FRAGMENT-MAJOR layout:
// element (row,k) -> ((row>>4)*(KD/32) + (k>>5))*512
//                    + (((k>>3)&3)*16 + (row&15))*8 + (k&7)
// so a wave's MFMA A-fragment load is base + lane*8 : one contiguous,
// fully-coalesced 1 KB read (was 16 scattered 64B lines).
// ===========================================================================
template <int KD>
__global__ __launch_bounds__(256) void convert_bf(
    const float* __restrict__ src, short* __restrict__ h, short* __restrict__ l,
    int nchunks)
{
    for (int t = blockIdx.x * 256 + threadIdx.x; t < nchunks; t += gridDim.x * 256) {
        int row = t / (KD / 8);
        int kc8 = t - row * (KD / 8);
        size_t sidx = (size_t)row * KD + (size_t)kc8 * 8;
        float4 v0 = *(const float4*)&src[sidx];
        float4 v1 = *(const float4*)&src[sidx + 4];
        float vv[8] = {v0.x, v0.y, v0.z, v0.w, v1.x, v1.y, v1.z, v1.w};
        bf16x8 hv, lv;
        #pragma unroll
        for (int e = 0; e < 8; ++e) {
            short hh = f2bf(vv[e]);
            hv[e] = hh;
            lv[e] = f2bf(vv[e] - bf2f(hh));
        }
        size_t dst = ((size_t)((row >> 4) * (KD / 32) + (kc8 >> 2))) * 512
                   + (size_t)(((kc8 & 3) * 16 + (row & 15)) * 8);
        *(bf16x8*)&h[dst] = hv;
        *(bf16x8*)&l[dst] = lv;
    }
}

// ===========================================================================
// bf16x3 MFMA GEMM: part[kslice] = A[all 256 rows, kslice] @ B[kslice, ntile]
// BM=256 (Wb streamed once), BN=256, BK=64, 1024 threads = 16 waves (4x4),
// wave tile 64x64. blockIdx.x = K-SLICE (XCD pin: linear id % 8 = k-slice,
// so the 32 blocks sharing one 1 MB A-slice co-locate on one XCD's L2).
// A-frags: coalesced 1KB loads from fragment-major planes (L2-resident).
// B double-buffered 128 KB LDS; raw s_barrier + lgkmcnt only; prefetch
// 2 steps deep stays in flight across barriers (r8/r10-proven schedule).
// ===========================================================================
template <int KD, int BSTRIDE, int KPER, int SPLITZ, int SLICE>
__global__ __launch_bounds__(1024, 1) void gemm_mfma(
    const short* __restrict__ Ah_g, const short* __restrict__ Al_g,
    const float* __restrict__ Bg, float* __restrict__ part_w,
    float* __restrict__ part_d)
{
    // [buf][n][8 chunks of 8k], chunk pos = kc ^ (n&7)  (proven r3 swizzle)
    __shared__ short Bh[2][256 * 64];   // 64 KB
    __shared__ short Bl[2][256 * 64];   // 64 KB

    const int tid = threadIdx.x;
    const int l = tid & 63;
    const int w = tid >> 6;             // 0..15
    const int wr = w >> 2;              // wave row band (0..3), 64 rows
    const int wc = w & 3;               // wave col band (0..3), 64 cols
    const int z  = blockIdx.x;          // K-SLICE (XCD-pinned)
    const int n0 = blockIdx.y * 256;
    const int k0 = z * KPER;
    constexpr int NSTEP = KPER / 64;

    // staging map: thread covers 4 k-rows x 4 n (16 elems), all 1024 stage
    const int khalf = tid & 1;          // half-chunk (4 k)
    const int kc    = (tid >> 1) & 7;   // 8-k chunk
    const int n4    = (tid >> 4) * 4;   // n quad (0..252)

    f32x4 acc[4][4] = {};
    float4 f[4];

    // prologue: load + convert step 0 into buf 0; issue step-1 loads
    #pragma unroll
    for (int it = 0; it < 4; ++it)
        f[it] = *(const float4*)&Bg[(size_t)(k0 + kc * 8 + khalf * 4 + it) * BSTRIDE + n0 + n4];
    #pragma unroll
    for (int j = 0; j < 4; ++j) {
        s16x4 hv, lv;
        #pragma unroll
        for (int it = 0; it < 4; ++it) {
            float v = ((const float*)&f[it])[j];
            short hh = f2bf(v);
            hv[it] = hh;
            lv[it] = f2bf(v - bf2f(hh));
        }
        int n = n4 + j;
        int off = n * 64 + ((kc ^ (n & 7)) * 8) + khalf * 4;
        *(s16x4*)&Bh[0][off] = hv;
        *(s16x4*)&Bl[0][off] = lv;
    }
    if (NSTEP > 1) {
        #pragma unroll
        for (int it = 0; it < 4; ++it)
            f[it] = *(const float4*)&Bg[(size_t)(k0 + 64 + kc * 8 + khalf * 4 + it) * BSTRIDE + n0 + n4];
    }

    for (int st = 0; st < NSTEP; ++st) {
        const int cur = st & 1;
        const int kw = k0 + st * 64;

        // own LDS writes (convert of buf[cur]) must drain; NOT vmcnt.
        asm volatile("s_waitcnt lgkmcnt(0)" ::: "memory");
        __builtin_amdgcn_sched_barrier(0);
        __builtin_amdgcn_s_barrier();
        __builtin_amdgcn_sched_barrier(0);

        // convert step st+1 into buf[cur^1]; f regs die before frags go live
        if (st + 1 < NSTEP) {
            #pragma unroll
            for (int j = 0; j < 4; ++j) {
                s16x4 hv, lv;
                #pragma unroll
                for (int it = 0; it < 4; ++it) {
                    float v = ((const float*)&f[it])[j];
                    short hh = f2bf(v);
                    hv[it] = hh;
                    lv[it] = f2bf(v - bf2f(hh));
                }
                int n = n4 + j;
                int off = n * 64 + ((kc ^ (n & 7)) * 8) + khalf * 4;
                *(s16x4*)&Bh[cur ^ 1][off] = hv;
                *(s16x4*)&Bl[cur ^ 1][off] = lv;
            }
        }
        // issue loads for step st+2
        if (st + 2 < NSTEP) {
            const int kn = kw + 128;
            #pragma unroll
            for (int it = 0; it < 4; ++it)
                f[it] = *(const float4*)&Bg[(size_t)(kn + kc * 8 + khalf * 4 + it) * BSTRIDE + n0 + n4];
        }

        // compute step st: A-frags coalesced from fragment-major planes
        #pragma unroll
        for (int kk = 0; kk < 2; ++kk) {
            bf16x8 ah[4], al[4];
            #pragma unroll
            for (int mt = 0; mt < 4; ++mt) {
                size_t base = ((size_t)((wr * 4 + mt) * (KD / 32) + (kw >> 5) + kk)) * 512
                            + (size_t)l * 8;
                ah[mt] = *(const bf16x8*)&Ah_g[base];
                al[mt] = *(const bf16x8*)&Al_g[base];
            }
            const int chunk = kk * 4 + (l >> 4);
            #pragma unroll
            for (int nt = 0; nt < 4; ++nt) {
                int n = wc * 64 + nt * 16 + (l & 15);
                int off = n * 64 + ((chunk ^ (n & 7)) * 8);
                bf16x8 bh = *(const bf16x8*)&Bh[cur][off];
                bf16x8 bl = *(const bf16x8*)&Bl[cur][off];
                #pragma unroll
                for (int mt = 0; mt < 4; ++mt) {
                    acc[mt][nt] = __builtin_amdgcn_mfma_f32_16x16x32_bf16(
                        ah[mt], bh, acc[mt][nt], 0, 0, 0);
                    acc[mt][nt] = __builtin_amdgcn_mfma_f32_16x16x32_bf16(
                        ah[mt], bl, acc[mt][nt], 0, 0, 0);
                    acc[mt][nt] = __builtin_amdgcn_mfma_f32_16x16x32_bf16(
                        al[mt], bh, acc[mt][nt], 0, 0, 0);
                }
            }
        }
        // no trailing barrier: next convert targets the OTHER buffer.
    }

    // Epilogue: D layout col = lane&15, row = (lane>>4)*4 + reg
    float* P = (z < SPLITZ) ? (part_w + (size_t)z * SLICE)
                            : (part_d + (size_t)(z - SPLITZ) * SLICE);
    #pragma unroll
    for (int mt = 0; mt < 4; ++mt) {
        int m = wr * 64 + mt * 16 + (l >> 4) * 4;
        #pragma unroll
        for (int nt = 0; nt < 4; ++nt) {
            int n = n0 + wc * 64 + nt * 16 + (l & 15);
            #pragma unroll
            for (int r = 0; r < 4; ++r)
                P[(size_t)(m + r) * BSTRIDE + n] = acc[mt][nt][r];
        }
    }
}

// Partial reduce + bias (+ z_a repeat + global-min for MODE 1).
// Slices 0..NSLW-1 at pw, then NSLD more at pd (fixed order -> deterministic).
// `out` may alias pw slice 0 (element-wise read-then-write) -> no __restrict__.
template <int NSLW, int NSLD, int NDIM, int MODE, int STR4>
__global__ __launch_bounds__(256) void reduce_part(
    const float* pw, const float* pd, const float* __restrict__ aux,
    const float* __restrict__ bias, float* out,
    float* __restrict__ bmin)
{
    __shared__ float red[256];
    int i = blockIdx.x * 256 + threadIdx.x;
    size_t b4 = (size_t)i * 4;
    float4 s = {0.f, 0.f, 0.f, 0.f};
    #pragma unroll
    for (int sl = 0; sl < NSLW; ++sl) {
        float4 p = *(const float4*)&pw[(size_t)sl * STR4 * 4 + b4];
        s.x += p.x; s.y += p.y; s.z += p.z; s.w += p.w;
    }
    #pragma unroll
    for (int sl = 0; sl < NSLD; ++sl) {
        float4 p = *(const float4*)&pd[(size_t)sl * STR4 * 4 + b4];
        s.x += p.x; s.y += p.y; s.z += p.z; s.w += p.w;
    }
    int col = (int)(b4 & (NDIM - 1));
    float4 bv = *(const float4*)&bias[col];
    float az = 0.f;
    if (MODE == 1) {
        int m = (int)(b4 >> 13);
        az = aux[m * MG + (col >> 3)];
    }
    s.x += bv.x + az; s.y += bv.y + az; s.z += bv.z + az; s.w += bv.w + az;
    *(float4*)&out[b4] = s;

    if (MODE == 1) {
        float v = fminf(fminf(s.x, s.y), fminf(s.z, s.w));
        red[threadIdx.x] = v;
        __syncthreads();
        for (int st = 128; st > 0; st >>= 1) {
            if (threadIdx.x < st)
                red[threadIdx.x] = fminf(red[threadIdx.x], red[threadIdx.x + st]);
            __syncthreads();
        }
        if (threadIdx.x == 0) bmin[blockIdx.x] = red[0];
    }
}

// ---------------------------------------------------------------------------
extern "C" void kernel_launch(void* const* d_in, const int* in_sizes, int n_in,
                              void* d_out, int out_size, void* d_ws, size_t ws_size,
                              hipStream_t stream)
{
    const float* x_a = (const float*)d_in[0];
    const float* x_b = (const float*)d_in[1];
    const float* phi = (const float*)d_in[2];
    const float* psi = (const float*)d_in[3];
    const float* Wa  = (const float*)d_in[4];
    const float* ba  = (const float*)d_in[5];
    const float* Wb  = (const float*)d_in[6];
    const float* bb  = (const float*)d_in[7];
    const float* Wd  = (const float*)d_in[8];
    const float* bd  = (const float*)d_in[9];

    float* out = (float*)d_out;
    float* pred    = out;
    float* xb_new  = out + BSZ * D_OUT;
    float* phi_new = out + BSZ * D_OUT + BSZ * TOTAL;
    float* psi_new = out + BSZ * D_OUT + 2 * BSZ * TOTAL;

    float* ws = (float*)d_ws;
    dim3 blk(256);
    dim3 blk512(512);
    dim3 blk1024(1024);

    // Workspace layout (float offsets); all 16B-aligned.
    const size_t OFF_ZA     = 0;            // 262144
    const size_t OFF_DECODE = 262144;       // 262144
    const size_t OFF_BMIN   = 524288;       // 2048
    const size_t OFF_MINV   = 526336;       // 16
    const size_t OFF_XBH    = 526352;       // 1048576 (2M shorts)
    const size_t OFF_XBL    = 1574928;      // 1048576
    const size_t OFF_PART   = 2623504;      // 10485760 floats (5 sigma slices)
    const size_t NEED = (OFF_PART + 10485760) * 4;   // 52437056 B == r3-proven

    if (ws_size >= NEED) {
        float* z_a    = ws + OFF_ZA;
        float* decode = ws + OFF_DECODE;
        float* bmin   = ws + OFF_BMIN;
        float* minv   = ws + OFF_MINV;
        short* xbh    = (short*)(ws + OFF_XBH);
        short* xbl    = (short*)(ws + OFF_XBL);
        short* dech   = xbh;                  // reuse (sigma gemm done by then)
        short* decl   = xbl;
        float* part_w = ws + OFF_PART;        // 5 slices of 2097152 floats
        float* part_d = out + BSZ * D_OUT;    // 3 slices in d_out (dead until
                                              // row_kernel overwrites them)
        float* sigma  = part_w;               // alias, slice 0

        // z_a = x_a @ Wa + ba  -- fp32 (decision-grade accuracy; feeds top-k)
        gemm_f32<0><<<dim3(MG / TILE, BSZ / TILE), blk, 0, stream>>>(
            x_a, Wa, ba, nullptr, z_a, BSZ, MG, D_IN);

        // sigma = repeat(z_a,8) + x_b @ Wb + bb  -- bf16x3 MFMA
        convert_bf<TOTAL><<<1024, blk, 0, stream>>>(x_b, xbh, xbl, BSZ * TOTAL / 8);
        gemm_mfma<TOTAL, TOTAL, 1024, 5, BSZ * TOTAL>
            <<<dim3(8, 32), blk1024, 0, stream>>>(
                xbh, xbl, Wb, part_w, part_d);
        reduce_part<5, 3, TOTAL, 1, 524288><<<2048, blk, 0, stream>>>(
            part_w, part_d, z_a, bb, sigma, bmin);
        block_min<<<1, blk, 0, stream>>>(bmin, 2048, minv);

        // masks, y, elementwise outputs, decode_in (consumes sigma; overwrites
        // the d_out partial slices, which are dead now)
        row_kernel<<<BSZ, blk512, 0, stream>>>(
            sigma, phi, psi, minv, decode, xb_new, phi_new, psi_new);

        // pred = decode @ Wd + bd  -- bf16x3 MFMA (no decisions downstream)
        convert_bf<MG><<<128, blk, 0, stream>>>(decode, dech, decl, BSZ * MG / 8);
        gemm_mfma<MG, D_OUT, 64, 16, BSZ * D_OUT>
            <<<dim3(16, 8), blk1024, 0, stream>>>(
                dech, decl, Wd, part_w, part_w);
        reduce_part<16, 0, D_OUT, 2, 131072><<<512, blk, 0, stream>>>(
            part_w, part_w, nullptr, bd, pred, nullptr);
    } else {
        // Fallback: proven fp32 path (needs ~10.5 MB ws)
        float* z_a    = ws;
        float* sigma  = ws + 262144;
        float* decode = ws + 262144 + 2097152;
        float* bmin   = ws + 2621440;
        float* minv   = ws + 2622464;

        gemm_f32<0><<<dim3(MG / TILE, BSZ / TILE), blk, 0, stream>>>(
            x_a, Wa, ba, nullptr, z_a, BSZ, MG, D_IN);
        gemm_f32<1><<<dim3(TOTAL / TILE, BSZ / TILE), blk, 0, stream>>>(
            x_b, Wb, bb, z_a, sigma, BSZ, TOTAL, TOTAL);
        block_min<<<1024, blk, 0, stream>>>(sigma, BSZ * TOTAL, bmin);
        block_min<<<1, blk, 0, stream>>>(bmin, 1024, minv);
        row_kernel<<<BSZ, blk512, 0, stream>>>(
            sigma, phi, psi, minv, decode, xb_new, phi_new, psi_new);
        gemm_f32<0><<<dim3(D_OUT / TILE, BSZ / TILE), blk, 0, stream>>>(
            decode, Wd, bd, nullptr, pred, BSZ, D_OUT, MG);
    }
}

// Round 12
// 256.627 us; speedup vs baseline: 1.7996x; 1.3107x over previous
//
#include <hip/hip_runtime.h>
#include <hip/hip_bf16.h>
#include <cmath>

// Problem constants
#define BSZ      256
#define D_IN     2048
#define D_OUT    2048
#define MG       1024      // M_GROUPS
#define NC       8         // N_CELLS
#define TOTAL    8192      // MG*NC
#define KGRP     128       // K_GROUPS (top-k groups)

typedef short bf16x8 __attribute__((ext_vector_type(8)));
typedef short s16x4  __attribute__((ext_vector_type(4)));
typedef float f32x4  __attribute__((ext_vector_type(4)));

// fp32 <-> bf16 helpers (round-to-nearest-even, bit ops, deterministic)
__device__ inline short f2bf(float f) {
    unsigned u = __float_as_uint(f);
    unsigned r = (u + 0x7fffu + ((u >> 16) & 1u)) >> 16;
    return (short)r;
}
__device__ inline float bf2f(short s) {
    return __uint_as_float(((unsigned)(unsigned short)s) << 16);
}

// ===========================================================================
// fp32 tiled GEMM (z_a producer — decision-grade accuracy — and fallback)
// ===========================================================================
#define TILE 64
#define BK   32

template <int MODE>
__global__ __launch_bounds__(256) void gemm_f32(
    const float* __restrict__ A, const float* __restrict__ B,
    const float* __restrict__ bias, const float* __restrict__ aux,
    float* __restrict__ C, int M, int N, int K)
{
    __shared__ float As[BK][TILE + 4];
    __shared__ float Bs[BK][TILE];

    const int tid = threadIdx.x;
    const int tx = tid & 15;
    const int ty = tid >> 4;
    const int n0 = blockIdx.x * TILE;
    const int m0 = blockIdx.y * TILE;

    float acc[4][4] = {};

    for (int k0 = 0; k0 < K; k0 += BK) {
        #pragma unroll
        for (int it = 0; it < 2; ++it) {
            int lin = tid + it * 256;
            int row = lin >> 3;
            int c4  = lin & 7;
            float4 a = *(const float4*)&A[(size_t)(m0 + row) * K + k0 + c4 * 4];
            As[c4 * 4 + 0][row] = a.x;
            As[c4 * 4 + 1][row] = a.y;
            As[c4 * 4 + 2][row] = a.z;
            As[c4 * 4 + 3][row] = a.w;
        }
        #pragma unroll
        for (int it = 0; it < 2; ++it) {
            int lin = tid + it * 256;
            int row = lin >> 4;
            int c4  = lin & 15;
            *(float4*)&Bs[row][c4 * 4] =
                *(const float4*)&B[(size_t)(k0 + row) * N + n0 + c4 * 4];
        }
        __syncthreads();

        #pragma unroll
        for (int k = 0; k < BK; ++k) {
            float4 av = *(const float4*)&As[k][ty * 4];
            float4 bv = *(const float4*)&Bs[k][tx * 4];
            float a_[4] = {av.x, av.y, av.z, av.w};
            float b_[4] = {bv.x, bv.y, bv.z, bv.w};
            #pragma unroll
            for (int i = 0; i < 4; ++i)
                #pragma unroll
                for (int j = 0; j < 4; ++j)
                    acc[i][j] = fmaf(a_[i], b_[j], acc[i][j]);
        }
        __syncthreads();
    }

    #pragma unroll
    for (int i = 0; i < 4; ++i) {
        int m = m0 + ty * 4 + i;
        int n = n0 + tx * 4;
        float4 out;
        float* o = (float*)&out;
        #pragma unroll
        for (int j = 0; j < 4; ++j) {
            float v = acc[i][j] + bias[n + j];
            if (MODE == 1) v = aux[(size_t)m * MG + ((n + j) >> 3)] + v;
            o[j] = v;
        }
        *(float4*)&C[(size_t)m * N + n] = out;
    }
}

// K-split fp32 GEMM (no bias): C[z] = A[:, z*KSP:(z+1)*KSP] @ B[slice, tile]
template <int KSP>
__global__ __launch_bounds__(256) void gemm_f32_ks(
    const float* __restrict__ A, const float* __restrict__ B,
    float* __restrict__ C, int M, int N, int K)
{
    __shared__ float As[BK][TILE + 4];
    __shared__ float Bs[BK][TILE];

    const int tid = threadIdx.x;
    const int tx = tid & 15;
    const int ty = tid >> 4;
    const int n0 = blockIdx.x * TILE;
    const int m0 = blockIdx.y * TILE;
    const int kbeg = blockIdx.z * KSP;

    float acc[4][4] = {};

    for (int k0 = kbeg; k0 < kbeg + KSP; k0 += BK) {
        #pragma unroll
        for (int it = 0; it < 2; ++it) {
            int lin = tid + it * 256;
            int row = lin >> 3;
            int c4  = lin & 7;
            float4 a = *(const float4*)&A[(size_t)(m0 + row) * K + k0 + c4 * 4];
            As[c4 * 4 + 0][row] = a.x;
            As[c4 * 4 + 1][row] = a.y;
            As[c4 * 4 + 2][row] = a.z;
            As[c4 * 4 + 3][row] = a.w;
        }
        #pragma unroll
        for (int it = 0; it < 2; ++it) {
            int lin = tid + it * 256;
            int row = lin >> 4;
            int c4  = lin & 15;
            *(float4*)&Bs[row][c4 * 4] =
                *(const float4*)&B[(size_t)(k0 + row) * N + n0 + c4 * 4];
        }
        __syncthreads();

        #pragma unroll
        for (int k = 0; k < BK; ++k) {
            float4 av = *(const float4*)&As[k][ty * 4];
            float4 bv = *(const float4*)&Bs[k][tx * 4];
            float a_[4] = {av.x, av.y, av.z, av.w};
            float b_[4] = {bv.x, bv.y, bv.z, bv.w};
            #pragma unroll
            for (int i = 0; i < 4; ++i)
                #pragma unroll
                for (int j = 0; j < 4; ++j)
                    acc[i][j] = fmaf(a_[i], b_[j], acc[i][j]);
        }
        __syncthreads();
    }

    float* Cz = C + (size_t)blockIdx.z * M * N;
    #pragma unroll
    for (int i = 0; i < 4; ++i) {
        int m = m0 + ty * 4 + i;
        int n = n0 + tx * 4;
        float4 out;
        float* o = (float*)&out;
        #pragma unroll
        for (int j = 0; j < 4; ++j) o[j] = acc[i][j];
        *(float4*)&Cz[(size_t)m * N + n] = out;
    }
}

__global__ __launch_bounds__(256) void block_min(
    const float* __restrict__ x, int n, float* __restrict__ out)
{
    __shared__ float red[256];
    float v = 3.402823466e+38f;
    for (int i = blockIdx.x * 256 + threadIdx.x; i < n; i += gridDim.x * 256)
        v = fminf(v, x[i]);
    red[threadIdx.x] = v;
    __syncthreads();
    for (int s = 128; s > 0; s >>= 1) {
        if (threadIdx.x < s)
            red[threadIdx.x] = fminf(red[threadIdx.x], red[threadIdx.x + s]);
        __syncthreads();
    }
    if (threadIdx.x == 0) out[blockIdx.x] = red[0];
}

// ===========================================================================
// row_kernel v2: top-128 selection via 32-bit max-threshold binary search
// (keys in REGISTERS; 33 shfl-reduce count passes) instead of 55-pass bitonic.
// Tie semantics == jax top_k: strictly-greater first, then equal values by
// ascending group index (ballot/popcount prefix in g order).
// ===========================================================================
__global__ __launch_bounds__(512) void row_kernel(
    const float* __restrict__ sigma, const float* __restrict__ phi,
    const float* __restrict__ psi, const float* __restrict__ minval,
    float* __restrict__ decode, float* __restrict__ xb_new,
    float* __restrict__ phi_new, float* __restrict__ psi_new)
{
    __shared__ int acell[MG];
    __shared__ int win[MG];
    __shared__ int wsum[8];
    __shared__ int csum[16];

    const int b = blockIdx.x;
    const int tid = threadIdx.x;
    const int lane = tid & 63;
    const int wid = tid >> 6;           // 0..7
    const float smin = minval[0];
    const float* srow = sigma + (size_t)b * TOTAL;
    const float* prow = phi + (size_t)b * TOTAL;
    const float* qrow = psi + (size_t)b * TOTAL;

    // Phase A: per-group lambda (monotone uint key, kept in registers) + argmax
    unsigned u0 = 0, u1 = 0;
    #pragma unroll
    for (int slot = 0; slot < 2; ++slot) {
        int g = tid + slot * 512;
        float best = -3.402823466e+38f;
        int bc = 0;
        #pragma unroll
        for (int c = 0; c < NC; ++c) {
            float s = srow[g * NC + c];
            float p = prow[g * NC + c];
            float pi = (1.0f - p) * ((s - smin) + 1.0f);
            if (pi > best) { best = pi; bc = c; }
        }
        unsigned bits = __float_as_uint(best);
        unsigned u = (bits & 0x80000000u) ? ~bits : (bits | 0x80000000u);
        if (slot == 0) u0 = u; else u1 = u;
        acell[g] = bc;
    }

    // Phase B: find V = value of the 128th-largest key (max V with cnt>=128)
    unsigned V = 0;
    #pragma unroll 1
    for (int bit = 31; bit >= 0; --bit) {
        unsigned cand = V | (1u << bit);
        int c = (int)(u0 >= cand) + (int)(u1 >= cand);
        #pragma unroll
        for (int off = 32; off > 0; off >>= 1) c += __shfl_down(c, off);
        if (lane == 0) wsum[wid] = c;
        __syncthreads();
        int tot = wsum[0] + wsum[1] + wsum[2] + wsum[3]
                + wsum[4] + wsum[5] + wsum[6] + wsum[7];
        __syncthreads();
        if (tot >= KGRP) V = cand;
    }
    // count strictly-above
    {
        int c = (int)(u0 > V) + (int)(u1 > V);
        #pragma unroll
        for (int off = 32; off > 0; off >>= 1) c += __shfl_down(c, off);
        if (lane == 0) wsum[wid] = c;
        __syncthreads();
    }
    int nAbove = wsum[0] + wsum[1] + wsum[2] + wsum[3]
               + wsum[4] + wsum[5] + wsum[6] + wsum[7];
    int need = KGRP - nAbove;           // >= 1 by construction of V

    // equal-set rank in ascending-g order (first-index-wins)
    unsigned long long m0 = __ballot(u0 == V);
    unsigned long long m1 = __ballot(u1 == V);
    if (lane == 0) {
        csum[wid]     = __popcll(m0);   // chunk = g/64 for slot0: 0..7
        csum[8 + wid] = __popcll(m1);   // slot1: chunks 8..15
    }
    __syncthreads();
    unsigned long long below = (lane == 0) ? 0ull : ((~0ull) >> (64 - lane));
    {
        int pre0 = 0;
        for (int c = 0; c < 8; ++c) if (c < wid) pre0 += csum[c];
        int rank0 = pre0 + (int)__popcll(m0 & below);
        int pre1 = 0;
        for (int c = 0; c < 16; ++c) if (c < 8 + wid) pre1 += csum[c];
        int rank1 = pre1 + (int)__popcll(m1 & below);
        win[tid]       = (u0 > V) || (u0 == V && rank0 < need);
        win[tid + 512] = (u1 > V) || (u1 == V && rank1 < need);
    }
    __syncthreads();

    // Phase C: y + elementwise outputs
    for (int j = tid; j < TOTAL; j += 512) {
        int g = j >> 3, c = j & 7;
        float s = srow[j];
        float y = 0.0f;
        if (win[g] && acell[g] == c) y = tanhf(s);
        float pn = fmaxf(prow[j] * 0.5f, y);
        float qn = fmaxf(qrow[j] * 0.5f, y);
        phi_new[(size_t)b * TOTAL + j] = pn;
        psi_new[(size_t)b * TOTAL + j] = qn;
        xb_new[(size_t)b * TOTAL + j] = qn;
    }

    // Phase D: decode_in
    for (int g = tid; g < MG; g += 512) {
        float d = 0.0f;
        if (win[g]) d = fmaxf(0.0f, tanhf(srow[g * NC + acell[g]]));
        decode[(size_t)b * MG + g] = d;
    }
}

// ===========================================================================
// A-plane conversion, FRAGMENT-MAJOR layout (r11-proven):
// element (row,k) -> ((row>>4)*(KD/32) + (k>>5))*512
//                    + (((k>>3)&3)*16 + (row&15))*8 + (k&7)
// ===========================================================================
template <int KD>
__global__ __launch_bounds__(256) void convert_bf(
    const float* __restrict__ src, short* __restrict__ h, short* __restrict__ l,
    int nchunks)
{
    for (int t = blockIdx.x * 256 + threadIdx.x; t < nchunks; t += gridDim.x * 256) {
        int row = t / (KD / 8);
        int kc8 = t - row * (KD / 8);
        size_t sidx = (size_t)row * KD + (size_t)kc8 * 8;
        float4 v0 = *(const float4*)&src[sidx];
        float4 v1 = *(const float4*)&src[sidx + 4];
        float vv[8] = {v0.x, v0.y, v0.z, v0.w, v1.x, v1.y, v1.z, v1.w};
        bf16x8 hv, lv;
        #pragma unroll
        for (int e = 0; e < 8; ++e) {
            short hh = f2bf(vv[e]);
            hv[e] = hh;
            lv[e] = f2bf(vv[e] - bf2f(hh));
        }
        size_t dst = ((size_t)((row >> 4) * (KD / 32) + (kc8 >> 2))) * 512
                   + (size_t)(((kc8 & 3) * 16 + (row & 15)) * 8);
        *(bf16x8*)&h[dst] = hv;
        *(bf16x8*)&l[dst] = lv;
    }
}

// ===========================================================================
// bf16x3 MFMA GEMM (r11-proven, UNTOUCHED): BM=256, BN=256, BK=64,
// 1024 threads = 16 waves (4x4), wave tile 64x64. blockIdx.x = K-SLICE
// (XCD pin). A-frags coalesced from fragment-major planes (L2-resident).
// B dbuf 128 KB LDS; raw s_barrier + lgkmcnt; 2-step-deep prefetch.
// ===========================================================================
template <int KD, int BSTRIDE, int KPER, int SPLITZ, int SLICE>
__global__ __launch_bounds__(1024, 1) void gemm_mfma(
    const short* __restrict__ Ah_g, const short* __restrict__ Al_g,
    const float* __restrict__ Bg, float* __restrict__ part_w,
    float* __restrict__ part_d)
{
    __shared__ short Bh[2][256 * 64];   // 64 KB
    __shared__ short Bl[2][256 * 64];   // 64 KB

    const int tid = threadIdx.x;
    const int l = tid & 63;
    const int w = tid >> 6;
    const int wr = w >> 2;
    const int wc = w & 3;
    const int z  = blockIdx.x;
    const int n0 = blockIdx.y * 256;
    const int k0 = z * KPER;
    constexpr int NSTEP = KPER / 64;

    const int khalf = tid & 1;
    const int kc    = (tid >> 1) & 7;
    const int n4    = (tid >> 4) * 4;

    f32x4 acc[4][4] = {};
    float4 f[4];

    #pragma unroll
    for (int it = 0; it < 4; ++it)
        f[it] = *(const float4*)&Bg[(size_t)(k0 + kc * 8 + khalf * 4 + it) * BSTRIDE + n0 + n4];
    #pragma unroll
    for (int j = 0; j < 4; ++j) {
        s16x4 hv, lv;
        #pragma unroll
        for (int it = 0; it < 4; ++it) {
            float v = ((const float*)&f[it])[j];
            short hh = f2bf(v);
            hv[it] = hh;
            lv[it] = f2bf(v - bf2f(hh));
        }
        int n = n4 + j;
        int off = n * 64 + ((kc ^ (n & 7)) * 8) + khalf * 4;
        *(s16x4*)&Bh[0][off] = hv;
        *(s16x4*)&Bl[0][off] = lv;
    }
    if (NSTEP > 1) {
        #pragma unroll
        for (int it = 0; it < 4; ++it)
            f[it] = *(const float4*)&Bg[(size_t)(k0 + 64 + kc * 8 + khalf * 4 + it) * BSTRIDE + n0 + n4];
    }

    for (int st = 0; st < NSTEP; ++st) {
        const int cur = st & 1;
        const int kw = k0 + st * 64;

        asm volatile("s_waitcnt lgkmcnt(0)" ::: "memory");
        __builtin_amdgcn_sched_barrier(0);
        __builtin_amdgcn_s_barrier();
        __builtin_amdgcn_sched_barrier(0);

        if (st + 1 < NSTEP) {
            #pragma unroll
            for (int j = 0; j < 4; ++j) {
                s16x4 hv, lv;
                #pragma unroll
                for (int it = 0; it < 4; ++it) {
                    float v = ((const float*)&f[it])[j];
                    short hh = f2bf(v);
                    hv[it] = hh;
                    lv[it] = f2bf(v - bf2f(hh));
                }
                int n = n4 + j;
                int off = n * 64 + ((kc ^ (n & 7)) * 8) + khalf * 4;
                *(s16x4*)&Bh[cur ^ 1][off] = hv;
                *(s16x4*)&Bl[cur ^ 1][off] = lv;
            }
        }
        if (st + 2 < NSTEP) {
            const int kn = kw + 128;
            #pragma unroll
            for (int it = 0; it < 4; ++it)
                f[it] = *(const float4*)&Bg[(size_t)(kn + kc * 8 + khalf * 4 + it) * BSTRIDE + n0 + n4];
        }

        #pragma unroll
        for (int kk = 0; kk < 2; ++kk) {
            bf16x8 ah[4], al[4];
            #pragma unroll
            for (int mt = 0; mt < 4; ++mt) {
                size_t base = ((size_t)((wr * 4 + mt) * (KD / 32) + (kw >> 5) + kk)) * 512
                            + (size_t)l * 8;
                ah[mt] = *(const bf16x8*)&Ah_g[base];
                al[mt] = *(const bf16x8*)&Al_g[base];
            }
            const int chunk = kk * 4 + (l >> 4);
            #pragma unroll
            for (int nt = 0; nt < 4; ++nt) {
                int n = wc * 64 + nt * 16 + (l & 15);
                int off = n * 64 + ((chunk ^ (n & 7)) * 8);
                bf16x8 bh = *(const bf16x8*)&Bh[cur][off];
                bf16x8 bl = *(const bf16x8*)&Bl[cur][off];
                #pragma unroll
                for (int mt = 0; mt < 4; ++mt) {
                    acc[mt][nt] = __builtin_amdgcn_mfma_f32_16x16x32_bf16(
                        ah[mt], bh, acc[mt][nt], 0, 0, 0);
                    acc[mt][nt] = __builtin_amdgcn_mfma_f32_16x16x32_bf16(
                        ah[mt], bl, acc[mt][nt], 0, 0, 0);
                    acc[mt][nt] = __builtin_amdgcn_mfma_f32_16x16x32_bf16(
                        al[mt], bh, acc[mt][nt], 0, 0, 0);
                }
            }
        }
    }

    float* P = (z < SPLITZ) ? (part_w + (size_t)z * SLICE)
                            : (part_d + (size_t)(z - SPLITZ) * SLICE);
    #pragma unroll
    for (int mt = 0; mt < 4; ++mt) {
        int m = wr * 64 + mt * 16 + (l >> 4) * 4;
        #pragma unroll
        for (int nt = 0; nt < 4; ++nt) {
            int n = n0 + wc * 64 + nt * 16 + (l & 15);
            #pragma unroll
            for (int r = 0; r < 4; ++r)
                P[(size_t)(m + r) * BSTRIDE + n] = acc[mt][nt][r];
        }
    }
}

// Partial reduce + bias (+ z_a repeat + global-min for MODE 1).
template <int NSLW, int NSLD, int NDIM, int MODE, int STR4>
__global__ __launch_bounds__(256) void reduce_part(
    const float* pw, const float* pd, const float* __restrict__ aux,
    const float* __restrict__ bias, float* out,
    float* __restrict__ bmin)
{
    __shared__ float red[256];
    int i = blockIdx.x * 256 + threadIdx.x;
    size_t b4 = (size_t)i * 4;
    float4 s = {0.f, 0.f, 0.f, 0.f};
    #pragma unroll
    for (int sl = 0; sl < NSLW; ++sl) {
        float4 p = *(const float4*)&pw[(size_t)sl * STR4 * 4 + b4];
        s.x += p.x; s.y += p.y; s.z += p.z; s.w += p.w;
    }
    #pragma unroll
    for (int sl = 0; sl < NSLD; ++sl) {
        float4 p = *(const float4*)&pd[(size_t)sl * STR4 * 4 + b4];
        s.x += p.x; s.y += p.y; s.z += p.z; s.w += p.w;
    }
    int col = (int)(b4 & (NDIM - 1));
    float4 bv = *(const float4*)&bias[col];
    float az = 0.f;
    if (MODE == 1) {
        int m = (int)(b4 >> 13);
        az = aux[m * MG + (col >> 3)];
    }
    s.x += bv.x + az; s.y += bv.y + az; s.z += bv.z + az; s.w += bv.w + az;
    *(float4*)&out[b4] = s;

    if (MODE == 1) {
        float v = fminf(fminf(s.x, s.y), fminf(s.z, s.w));
        red[threadIdx.x] = v;
        __syncthreads();
        for (int st = 128; st > 0; st >>= 1) {
            if (threadIdx.x < st)
                red[threadIdx.x] = fminf(red[threadIdx.x], red[threadIdx.x + st]);
            __syncthreads();
        }
        if (threadIdx.x == 0) bmin[blockIdx.x] = red[0];
    }
}

// ---------------------------------------------------------------------------
extern "C" void kernel_launch(void* const* d_in, const int* in_sizes, int n_in,
                              void* d_out, int out_size, void* d_ws, size_t ws_size,
                              hipStream_t stream)
{
    const float* x_a = (const float*)d_in[0];
    const float* x_b = (const float*)d_in[1];
    const float* phi = (const float*)d_in[2];
    const float* psi = (const float*)d_in[3];
    const float* Wa  = (const float*)d_in[4];
    const float* ba  = (const float*)d_in[5];
    const float* Wb  = (const float*)d_in[6];
    const float* bb  = (const float*)d_in[7];
    const float* Wd  = (const float*)d_in[8];
    const float* bd  = (const float*)d_in[9];

    float* out = (float*)d_out;
    float* pred    = out;
    float* xb_new  = out + BSZ * D_OUT;
    float* phi_new = out + BSZ * D_OUT + BSZ * TOTAL;
    float* psi_new = out + BSZ * D_OUT + 2 * BSZ * TOTAL;

    float* ws = (float*)d_ws;
    dim3 blk(256);
    dim3 blk512(512);
    dim3 blk1024(1024);

    // Workspace layout (float offsets); all 16B-aligned.
    const size_t OFF_ZA     = 0;            // 262144
    const size_t OFF_DECODE = 262144;       // 262144
    const size_t OFF_BMIN   = 524288;       // 2048
    const size_t OFF_MINV   = 526336;       // 16
    const size_t OFF_XBH    = 526352;       // 1048576 (2M shorts)
    const size_t OFF_XBL    = 1574928;      // 1048576
    const size_t OFF_PART   = 2623504;      // 10485760 floats (5 sigma slices)
    const size_t NEED = (OFF_PART + 10485760) * 4;   // 52437056 B == proven

    if (ws_size >= NEED) {
        float* z_a    = ws + OFF_ZA;
        float* decode = ws + OFF_DECODE;
        float* bmin   = ws + OFF_BMIN;
        float* minv   = ws + OFF_MINV;
        short* xbh    = (short*)(ws + OFF_XBH);
        short* xbl    = (short*)(ws + OFF_XBL);
        short* dech   = xbh;                  // reuse (sigma gemm done by then)
        short* decl   = xbl;
        float* part_w = ws + OFF_PART;        // 5 slices of 2097152 floats
        float* part_d = out + BSZ * D_OUT;    // 3 slices in d_out (dead until
                                              // row_kernel overwrites them)
        float* sigma  = part_w;               // alias, slice 0

        // z_a = x_a @ Wa + ba  -- fp32, K-split 4 (256 blocks); partials
        // transiently use part_w (dead until convert_bf/sigma gemm below)
        gemm_f32_ks<512><<<dim3(MG / TILE, BSZ / TILE, 4), blk, 0, stream>>>(
            x_a, Wa, part_w, BSZ, MG, D_IN);
        reduce_part<4, 0, MG, 0, 65536><<<256, blk, 0, stream>>>(
            part_w, part_w, nullptr, ba, z_a, nullptr);

        // sigma = repeat(z_a,8) + x_b @ Wb + bb  -- bf16x3 MFMA
        convert_bf<TOTAL><<<1024, blk, 0, stream>>>(x_b, xbh, xbl, BSZ * TOTAL / 8);
        gemm_mfma<TOTAL, TOTAL, 1024, 5, BSZ * TOTAL>
            <<<dim3(8, 32), blk1024, 0, stream>>>(
                xbh, xbl, Wb, part_w, part_d);
        reduce_part<5, 3, TOTAL, 1, 524288><<<2048, blk, 0, stream>>>(
            part_w, part_d, z_a, bb, sigma, bmin);
        block_min<<<1, blk, 0, stream>>>(bmin, 2048, minv);

        // masks, y, elementwise outputs, decode_in
        row_kernel<<<BSZ, blk512, 0, stream>>>(
            sigma, phi, psi, minv, decode, xb_new, phi_new, psi_new);

        // pred = decode @ Wd + bd  -- bf16x3 MFMA (no decisions downstream)
        convert_bf<MG><<<128, blk, 0, stream>>>(decode, dech, decl, BSZ * MG / 8);
        gemm_mfma<MG, D_OUT, 64, 16, BSZ * D_OUT>
            <<<dim3(16, 8), blk1024, 0, stream>>>(
                dech, decl, Wd, part_w, part_w);
        reduce_part<16, 0, D_OUT, 2, 131072><<<512, blk, 0, stream>>>(
            part_w, part_w, nullptr, bd, pred, nullptr);
    } else {
        // Fallback: proven fp32 path (needs ~10.5 MB ws)
        float* z_a    = ws;
        float* sigma  = ws + 262144;
        float* decode = ws + 262144 + 2097152;
        float* bmin   = ws + 2621440;
        float* minv   = ws + 2622464;

        gemm_f32<0><<<dim3(MG / TILE, BSZ / TILE), blk, 0, stream>>>(
            x_a, Wa, ba, nullptr, z_a, BSZ, MG, D_IN);
        gemm_f32<1><<<dim3(TOTAL / TILE, BSZ / TILE), blk, 0, stream>>>(
            x_b, Wb, bb, z_a, sigma, BSZ, TOTAL, TOTAL);
        block_min<<<1024, blk, 0, stream>>>(sigma, BSZ * TOTAL, bmin);
        block_min<<<1, blk, 0, stream>>>(bmin, 1024, minv);
        row_kernel<<<BSZ, blk512, 0, stream>>>(
            sigma, phi, psi, minv, decode, xb_new, phi_new, psi_new);
        gemm_f32<0><<<dim3(D_OUT / TILE, BSZ / TILE), blk, 0, stream>>>(
            decode, Wd, bd, nullptr, pred, BSZ, D_OUT, MG);
    }
}